// Round 2
// baseline (2252.660 us; speedup 1.0000x reference)
//
#include <hip/hip_runtime.h>

#define NN 50000
#define EE 800000
#define HH 128
#define GG 50
#define FF 128
#define SS 2
#define BB 256

typedef short bf16x8 __attribute__((ext_vector_type(8)));
typedef float floatx4 __attribute__((ext_vector_type(4)));

union FragU { bf16x8 v; unsigned short u[8]; unsigned int d[4]; uint4 q; };

__device__ __forceinline__ unsigned short f2bf(float f) {
    union { float f; unsigned int i; } c; c.f = f;
    unsigned int i = c.i;
    unsigned int r = (i + 0x7fffu + ((i >> 16) & 1u)) >> 16;
    return (unsigned short)r;
}
__device__ __forceinline__ float sspf(float x) {
    float l = __logf(1.f + __expf(x));
    l = (x > 20.f) ? x : l;
    return l - 0.69314718056f;
}
// convert 8 consecutive fp32 to a bf16 A/B fragment
__device__ __forceinline__ bf16x8 f8frag(const float* p) {
    FragU f;
#pragma unroll
    for (int j = 0; j < 8; j++) f.u[j] = f2bf(p[j]);
    return f.v;
}
__device__ __forceinline__ int clampi(int v, int hi) {
    v = (v < 0) ? 0 : v;
    return (v > hi) ? hi : v;
}

// ---------------- kPrep: batch histogram + state init ----------------
__global__ __launch_bounds__(256) void kPrep(const int* __restrict__ batch,
                                             int* __restrict__ counts,
                                             const float* __restrict__ sa_in,
                                             float* __restrict__ stateBuf) {
    int i = blockIdx.x * 256 + threadIdx.x;
    if (i < NN) atomicAdd(&counts[clampi(batch[i], BB - 1)], 1);
    if (i < BB * SS) stateBuf[i] = sa_in[i];
}

// ---------------- kA: h2 = lin1([sa,h]) ; xf = conv_lin1(h2) ----------------
__global__ __launch_bounds__(256) void kA(const float* __restrict__ hsrc,   // [N,128]
                                          const float* __restrict__ lin1w,  // [128,130]
                                          const float* __restrict__ lin1b,  // [128]
                                          const float* __restrict__ c1w,    // [128,128]
                                          const float* __restrict__ stateBuf, // [B,2]
                                          const int* __restrict__ batch,
                                          float* __restrict__ h2f,          // [N,128]
                                          float* __restrict__ xf) {         // [N,128]
    __shared__ __align__(16) unsigned short P[64][136];
    int lane = threadIdx.x & 63;
    int wave = threadIdx.x >> 6;
    int m = lane & 15, q = lane >> 4;
    int rowBase = blockIdx.x * 64 + wave * 16;
    int arow = rowBase + m;
    int arowc = (arow < NN) ? arow : (NN - 1);

    floatx4 acc[8];
#pragma unroll
    for (int t = 0; t < 8; t++) acc[t] = (floatx4){0.f, 0.f, 0.f, 0.f};

    // GEMM1: h @ Wh^T (Wh = lin1w cols [2..130), row stride 130)
#pragma unroll
    for (int k0 = 0; k0 < 128; k0 += 32) {
        bf16x8 a = f8frag(hsrc + (size_t)arowc * 128 + k0 + q * 8);
#pragma unroll
        for (int t = 0; t < 8; t++) {
            int n = t * 16 + m;
            bf16x8 b = f8frag(lin1w + (size_t)n * 130 + 2 + k0 + q * 8);
            acc[t] = __builtin_amdgcn_mfma_f32_16x16x32_bf16(a, b, acc[t], 0, 0, 0);
        }
    }

    // epilogue: + bias + state rank-2 term (fp32); h2 -> global fp32 + LDS bf16
    int r0 = rowBase + q * 4;
    float s0[4], s1[4];
#pragma unroll
    for (int j = 0; j < 4; j++) {
        int r = r0 + j; int rc = (r < NN) ? r : (NN - 1);
        int g = clampi(batch[rc], BB - 1);
        s0[j] = stateBuf[g * 2 + 0];
        s1[j] = stateBuf[g * 2 + 1];
    }
#pragma unroll
    for (int t = 0; t < 8; t++) {
        int c = t * 16 + m;
        float w0 = lin1w[(size_t)c * 130 + 0];
        float w1 = lin1w[(size_t)c * 130 + 1];
        float bb = lin1b[c];
#pragma unroll
        for (int j = 0; j < 4; j++) {
            int r = r0 + j;
            float v = acc[t][j] + bb + s0[j] * w0 + s1[j] * w1;
            if (r < NN) h2f[(size_t)r * 128 + c] = v;
            P[wave * 16 + q * 4 + j][c] = f2bf(v);
        }
    }
    __syncthreads();

    // GEMM2: xf = h2 @ conv_lin1^T
    floatx4 acc2[8];
#pragma unroll
    for (int t = 0; t < 8; t++) acc2[t] = (floatx4){0.f, 0.f, 0.f, 0.f};
#pragma unroll
    for (int k0 = 0; k0 < 128; k0 += 32) {
        FragU fa; fa.q = *(const uint4*)&P[wave * 16 + m][k0 + q * 8];
#pragma unroll
        for (int t = 0; t < 8; t++) {
            int n = t * 16 + m;
            bf16x8 b = f8frag(c1w + (size_t)n * 128 + k0 + q * 8);
            acc2[t] = __builtin_amdgcn_mfma_f32_16x16x32_bf16(fa.v, b, acc2[t], 0, 0, 0);
        }
    }
#pragma unroll
    for (int t = 0; t < 8; t++) {
        int c = t * 16 + m;
#pragma unroll
        for (int j = 0; j < 4; j++) {
            int r = r0 + j;
            if (r < NN) xf[(size_t)r * 128 + c] = acc2[t][j];
        }
    }
}

// ---------------- kE: edge MLP * cutoff * xf[src] -> atomic agg[dst] ----------------
__global__ __launch_bounds__(256) void kE(const float* __restrict__ ea,   // [E,50]
                                          const float* __restrict__ ew,   // [E]
                                          const float* __restrict__ w1,   // [128,50]
                                          const float* __restrict__ b1,   // [128]
                                          const float* __restrict__ w2,   // [128,128]
                                          const float* __restrict__ b2,   // [128]
                                          const int* __restrict__ eidx,   // [2,E]
                                          const float* __restrict__ xf,   // [N,128]
                                          float* __restrict__ agg) {      // [N,128]
    __shared__ __align__(16) unsigned short P[64][136];
    int lane = threadIdx.x & 63;
    int wave = threadIdx.x >> 6;
    int m = lane & 15, q = lane >> 4;
    int rowBase = blockIdx.x * 64 + wave * 16;   // E % 64 == 0

    floatx4 acc[8];
#pragma unroll
    for (int t = 0; t < 8; t++) acc[t] = (floatx4){0.f, 0.f, 0.f, 0.f};

    // GEMM1: edge_attr [.,50] @ mlp_w1^T, K padded 50->64 with masking
    {   // k0 = 0 : all k in [0,32) valid
        bf16x8 a = f8frag(ea + (size_t)(rowBase + m) * 50 + q * 8);
#pragma unroll
        for (int t = 0; t < 8; t++) {
            int n = t * 16 + m;
            bf16x8 b = f8frag(w1 + (size_t)n * 50 + q * 8);
            acc[t] = __builtin_amdgcn_mfma_f32_16x16x32_bf16(a, b, acc[t], 0, 0, 0);
        }
    }
    {   // k0 = 32 : mask k >= 50
        int kbase = 32 + q * 8;
        FragU fa;
        const float* pa = ea + (size_t)(rowBase + m) * 50 + kbase;
#pragma unroll
        for (int j = 0; j < 8; j++) fa.u[j] = (kbase + j < 50) ? f2bf(pa[j]) : 0;
#pragma unroll
        for (int t = 0; t < 8; t++) {
            int n = t * 16 + m;
            FragU fb;
            const float* pb = w1 + (size_t)n * 50 + kbase;
#pragma unroll
            for (int j = 0; j < 8; j++) fb.u[j] = (kbase + j < 50) ? f2bf(pb[j]) : 0;
            acc[t] = __builtin_amdgcn_mfma_f32_16x16x32_bf16(fa.v, fb.v, acc[t], 0, 0, 0);
        }
    }

    // P = ssp(acc + b1) -> LDS bf16
#pragma unroll
    for (int t = 0; t < 8; t++) {
        int c = t * 16 + m;
        float bb = b1[c];
#pragma unroll
        for (int j = 0; j < 4; j++)
            P[wave * 16 + q * 4 + j][c] = f2bf(sspf(acc[t][j] + bb));
    }
    __syncthreads();

    // GEMM2: P @ mlp_w2^T
    floatx4 acc2[8];
#pragma unroll
    for (int t = 0; t < 8; t++) acc2[t] = (floatx4){0.f, 0.f, 0.f, 0.f};
#pragma unroll
    for (int k0 = 0; k0 < 128; k0 += 32) {
        FragU fa; fa.q = *(const uint4*)&P[wave * 16 + m][k0 + q * 8];
#pragma unroll
        for (int t = 0; t < 8; t++) {
            int n = t * 16 + m;
            bf16x8 b = f8frag(w2 + (size_t)n * 128 + k0 + q * 8);
            acc2[t] = __builtin_amdgcn_mfma_f32_16x16x32_bf16(fa.v, b, acc2[t], 0, 0, 0);
        }
    }

    // epilogue: W = (acc2 + b2) * C(edge); msg = W * xf[src]; agg[dst] += msg
    int e0 = rowBase + q * 4;
    int srcj[4], dstj[4]; float Cj[4];
#pragma unroll
    for (int j = 0; j < 4; j++) {
        int e = e0 + j;
        srcj[j] = clampi(eidx[e], NN - 1);
        dstj[j] = clampi(eidx[EE + e], NN - 1);
        float w = ew[e];
        Cj[j] = 0.5f * (__cosf(w * 0.62831853072f) + 1.f);
    }
#pragma unroll
    for (int t = 0; t < 8; t++) {
        int c = t * 16 + m;
        float bb = b2[c];
#pragma unroll
        for (int j = 0; j < 4; j++) {
            float val = (acc2[t][j] + bb) * Cj[j] * xf[(size_t)srcj[j] * 128 + c];
            unsafeAtomicAdd(&agg[(size_t)dstj[j] * 128 + c], val);
        }
    }
}

// ---------------- kC: xc = conv_lin2(agg); h = h2 + ssp(xc); pooling ----------------
__global__ __launch_bounds__(256) void kC(const float* __restrict__ agg,  // [N,128]
                                          const float* __restrict__ w,    // [128,128]
                                          const float* __restrict__ b,    // [128]
                                          const float* __restrict__ h2f,  // [N,128]
                                          float* __restrict__ hn,         // [N,128] fp32 out
                                          const int* __restrict__ batch,
                                          float* __restrict__ pool,
                                          int doPool) {
    int lane = threadIdx.x & 63;
    int wave = threadIdx.x >> 6;
    int m = lane & 15, q = lane >> 4;
    int rowBase = blockIdx.x * 64 + wave * 16;
    int arow = rowBase + m;
    int arowc = (arow < NN) ? arow : (NN - 1);

    floatx4 acc[8];
#pragma unroll
    for (int t = 0; t < 8; t++) acc[t] = (floatx4){0.f, 0.f, 0.f, 0.f};

#pragma unroll
    for (int k0 = 0; k0 < 128; k0 += 32) {
        bf16x8 fa = f8frag(agg + (size_t)arowc * 128 + k0 + q * 8);
#pragma unroll
        for (int t = 0; t < 8; t++) {
            int n = t * 16 + m;
            bf16x8 bfr = f8frag(w + (size_t)n * 128 + k0 + q * 8);
            acc[t] = __builtin_amdgcn_mfma_f32_16x16x32_bf16(fa, bfr, acc[t], 0, 0, 0);
        }
    }

    int r0 = rowBase + q * 4;
    float vsum[4] = {0.f, 0.f, 0.f, 0.f};
#pragma unroll
    for (int t = 0; t < 8; t++) {
        int c = t * 16 + m;
        float bb = b[c];
#pragma unroll
        for (int j = 0; j < 4; j++) {
            int r = r0 + j; int rc = (r < NN) ? r : (NN - 1);
            float v = h2f[(size_t)rc * 128 + c] + sspf(acc[t][j] + bb);
            if (r < NN) {
                hn[(size_t)r * 128 + c] = v;
                vsum[j] += v;
            }
        }
    }
    if (doPool) {
#pragma unroll
        for (int j = 0; j < 4; j++) {
            float v = vsum[j];
#pragma unroll
            for (int off = 1; off < 16; off <<= 1) v += __shfl_xor(v, off, 16);
            int r = r0 + j;
            if (m == 0 && r < NN) unsafeAtomicAdd(&pool[clampi(batch[r], BB - 1)], v);
        }
    }
}

// ---------------- kS: state scalar = pooled mean row-sum ----------------
__global__ __launch_bounds__(256) void kS(const float* __restrict__ pool,
                                          const int* __restrict__ counts,
                                          float* __restrict__ stateBuf) {
    int b = threadIdx.x;
    if (b < BB) {
        float c = (float)counts[b];
        c = (c < 1.f) ? 1.f : c;
        float v = pool[b] / c;
        stateBuf[b * 2 + 0] = v;
        stateBuf[b * 2 + 1] = v;
    }
}

// ---------------- kOut: out = h @ out_w^T + out_b (fp32 store) ----------------
__global__ __launch_bounds__(256) void kOut(const float* __restrict__ hn,
                                            const float* __restrict__ ow,  // [128,128]
                                            const float* __restrict__ ob,  // [128]
                                            float* __restrict__ out) {
    int lane = threadIdx.x & 63;
    int wave = threadIdx.x >> 6;
    int m = lane & 15, q = lane >> 4;
    int rowBase = blockIdx.x * 64 + wave * 16;
    int arow = rowBase + m;
    int arowc = (arow < NN) ? arow : (NN - 1);

    floatx4 acc[8];
#pragma unroll
    for (int t = 0; t < 8; t++) acc[t] = (floatx4){0.f, 0.f, 0.f, 0.f};
#pragma unroll
    for (int k0 = 0; k0 < 128; k0 += 32) {
        bf16x8 a = f8frag(hn + (size_t)arowc * 128 + k0 + q * 8);
#pragma unroll
        for (int t = 0; t < 8; t++) {
            int n = t * 16 + m;
            bf16x8 bfr = f8frag(ow + (size_t)n * 128 + k0 + q * 8);
            acc[t] = __builtin_amdgcn_mfma_f32_16x16x32_bf16(a, bfr, acc[t], 0, 0, 0);
        }
    }
    int r0 = rowBase + q * 4;
#pragma unroll
    for (int t = 0; t < 8; t++) {
        int c = t * 16 + m;
        float bb = ob[c];
#pragma unroll
        for (int j = 0; j < 4; j++) {
            int r = r0 + j;
            if (r < NN) out[(size_t)r * 128 + c] = acc[t][j] + bb;
        }
    }
}

extern "C" void kernel_launch(void* const* d_in, const int* in_sizes, int n_in,
                              void* d_out, int out_size, void* d_ws, size_t ws_size,
                              hipStream_t stream) {
    const float* h     = (const float*)d_in[0];   // [N,128]
    const float* ew    = (const float*)d_in[1];   // [E]
    const float* ea    = (const float*)d_in[2];   // [E,50]
    const float* sa    = (const float*)d_in[3];   // [B,2]
    const float* lin1w = (const float*)d_in[4];   // [2,128,130]
    const float* lin1b = (const float*)d_in[5];   // [2,128]
    const float* mw1   = (const float*)d_in[6];   // [2,128,50]
    const float* mb1   = (const float*)d_in[7];   // [2,128]
    const float* mw2   = (const float*)d_in[8];   // [2,128,128]
    const float* mb2   = (const float*)d_in[9];   // [2,128]
    const float* c1w   = (const float*)d_in[10];  // [2,128,128]
    const float* c2w   = (const float*)d_in[11];  // [2,128,128]
    const float* c2b   = (const float*)d_in[12];  // [2,128]
    const float* outw  = (const float*)d_in[13];  // [128,128]
    const float* outb  = (const float*)d_in[14];  // [128]
    const int* eidx    = (const int*)d_in[15];    // [2,E]
    const int* batch   = (const int*)d_in[16];    // [N]
    float* out = (float*)d_out;

    char* ws = (char*)d_ws;
    float* h2f      = (float*)(ws);                         // 25,600,000 B
    float* xf       = (float*)(ws + 25600000);              // 25,600,000 B
    float* agg      = (float*)(ws + 51200000);              // 25,600,000 B
    float* hn       = (float*)(ws + 76800000);              // 25,600,000 B
    float* pool     = (float*)(ws + 102400000);             // 1024 B
    int* counts     = (int*)(ws + 102401024);               // 1024 B
    float* stateBuf = (float*)(ws + 102402048);             // 2048 B

    hipMemsetAsync(counts, 0, BB * 4, stream);
    hipMemsetAsync(pool, 0, BB * 4, stream);
    kPrep<<<(NN + 255) / 256, 256, 0, stream>>>(batch, counts, sa, stateBuf);

    const int gridN = (NN + 63) / 64;   // 782
    const int gridE = EE / 64;          // 12500

    for (int i = 0; i < 2; i++) {
        const float* hin = (i == 0) ? h : hn;
        hipMemsetAsync(agg, 0, (size_t)NN * 128 * 4, stream);
        kA<<<gridN, 256, 0, stream>>>(hin,
                                      lin1w + (size_t)i * 128 * 130,
                                      lin1b + (size_t)i * 128,
                                      c1w + (size_t)i * 128 * 128,
                                      stateBuf, batch, h2f, xf);
        kE<<<gridE, 256, 0, stream>>>(ea, ew,
                                      mw1 + (size_t)i * 128 * 50,
                                      mb1 + (size_t)i * 128,
                                      mw2 + (size_t)i * 128 * 128,
                                      mb2 + (size_t)i * 128,
                                      eidx, xf, agg);
        kC<<<gridN, 256, 0, stream>>>(agg,
                                      c2w + (size_t)i * 128 * 128,
                                      c2b + (size_t)i * 128,
                                      h2f, hn, batch, pool, (i == 0) ? 1 : 0);
        if (i == 0) kS<<<1, 256, 0, stream>>>(pool, counts, stateBuf);
    }
    kOut<<<gridN, 256, 0, stream>>>(hn, outw, outb, out);
}

// Round 3
// 1707.429 us; speedup vs baseline: 1.3193x; 1.3193x over previous
//
#include <hip/hip_runtime.h>

#define NN 50000
#define EE 800000
#define HH 128
#define GG 50
#define FF 128
#define SS 2
#define BB 256

typedef short bf16x8 __attribute__((ext_vector_type(8)));
typedef float floatx4 __attribute__((ext_vector_type(4)));

union FragU { bf16x8 v; unsigned short u[8]; unsigned int d[4]; uint4 q; };

__device__ __forceinline__ float bf2f(unsigned short u) {
    union { unsigned int i; float f; } c; c.i = ((unsigned int)u) << 16; return c.f;
}
__device__ __forceinline__ unsigned short f2bf(float f) {
    union { float f; unsigned int i; } c; c.f = f;
    unsigned int i = c.i;
    unsigned int r = (i + 0x7fffu + ((i >> 16) & 1u)) >> 16;
    return (unsigned short)r;
}
__device__ __forceinline__ float sspf(float x) {
    float l = __logf(1.f + __expf(x));
    l = (x > 20.f) ? x : l;
    return l - 0.69314718056f;
}
__device__ __forceinline__ bf16x8 f8frag(const float* p) {       // fp32 -> bf16 frag
    FragU f;
#pragma unroll
    for (int j = 0; j < 8; j++) f.u[j] = f2bf(p[j]);
    return f.v;
}
__device__ __forceinline__ bf16x8 load16(const unsigned short* p) { // 16B-aligned bf16
    FragU f; f.q = *(const uint4*)p; return f.v;
}
__device__ __forceinline__ bf16x8 loaddw(const unsigned short* p) { // 4B-aligned bf16
    FragU f; const unsigned int* pp = (const unsigned int*)p;
#pragma unroll
    for (int t = 0; t < 4; t++) f.d[t] = pp[t];
    return f.v;
}
__device__ __forceinline__ int clampi(int v, int hi) {
    v = (v < 0) ? 0 : v;
    return (v > hi) ? hi : v;
}

// ---------------- kConv: fp32 -> bf16 bulk convert ----------------
__global__ __launch_bounds__(256) void kConv(const float* __restrict__ s,
                                             unsigned short* __restrict__ d, int n) {
    for (int i = blockIdx.x * 256 + threadIdx.x; i < n; i += gridDim.x * 256)
        d[i] = f2bf(s[i]);
}

// ---------------- kPrep: batch histogram + state init ----------------
__global__ __launch_bounds__(256) void kPrep(const int* __restrict__ batch,
                                             int* __restrict__ counts,
                                             const float* __restrict__ sa_in,
                                             float* __restrict__ stateBuf) {
    int i = blockIdx.x * 256 + threadIdx.x;
    if (i < NN) atomicAdd(&counts[clampi(batch[i], BB - 1)], 1);
    if (i < BB * SS) stateBuf[i] = sa_in[i];
}

// ---------------- kHist: edges-per-dst histogram ----------------
__global__ __launch_bounds__(256) void kHist(const int* __restrict__ eidx,
                                             int* __restrict__ cnt) {
    for (int e = blockIdx.x * 256 + threadIdx.x; e < EE; e += gridDim.x * 256)
        atomicAdd(&cnt[clampi(eidx[EE + e], NN - 1)], 1);
}

// ---------------- kScan: exclusive scan of cnt[NN] -> off[NN] (1 block) ----------------
__global__ __launch_bounds__(1024) void kScan(const int* __restrict__ cnt,
                                              int* __restrict__ off) {
    __shared__ int s[1024];
    __shared__ int carry;
    int tid = threadIdx.x;
    if (tid == 0) carry = 0;
    __syncthreads();
    for (int base = 0; base < NN; base += 1024) {
        int v = (base + tid < NN) ? cnt[base + tid] : 0;
        s[tid] = v;
        __syncthreads();
#pragma unroll
        for (int o = 1; o < 1024; o <<= 1) {
            int x = (tid >= o) ? s[tid - o] : 0;
            __syncthreads();
            s[tid] += x;
            __syncthreads();
        }
        int incl = s[tid];
        int c0 = carry;
        if (base + tid < NN) off[base + tid] = c0 + incl - v;
        __syncthreads();
        if (tid == 0) carry = c0 + s[1023];
        __syncthreads();
    }
}

// ---------------- kScatter: build dst-sorted edge arrays ----------------
__global__ __launch_bounds__(256) void kScatter(const int* __restrict__ eidx,
                                                const float* __restrict__ ew,
                                                const int* __restrict__ off,
                                                int* __restrict__ cur,
                                                int* __restrict__ ePerm,
                                                int* __restrict__ dstS,
                                                int* __restrict__ srcS,
                                                float* __restrict__ cS) {
    for (int e = blockIdx.x * 256 + threadIdx.x; e < EE; e += gridDim.x * 256) {
        int d = clampi(eidx[EE + e], NN - 1);
        int pos = off[d] + atomicAdd(&cur[d], 1);
        ePerm[pos] = e;
        dstS[pos] = d;
        srcS[pos] = clampi(eidx[e], NN - 1);
        float w = ew[e];
        cS[pos] = 0.5f * (__cosf(w * 0.62831853072f) + 1.f);
    }
}

// ---------------- kA: h2 = lin1([sa,h]) ; xf = conv_lin1(h2) ----------------
__global__ __launch_bounds__(256) void kA(const unsigned short* __restrict__ hb,   // [N,128] bf16
                                          const unsigned short* __restrict__ l1wb, // [128,130] bf16
                                          const float* __restrict__ lin1w,         // [128,130] fp32 (state cols)
                                          const float* __restrict__ lin1b,
                                          const unsigned short* __restrict__ c1wb, // [128,128] bf16
                                          const float* __restrict__ stateBuf,
                                          const int* __restrict__ batch,
                                          float* __restrict__ h2f,                 // [N,128] fp32
                                          unsigned short* __restrict__ xfb) {      // [N,128] bf16
    __shared__ __align__(16) unsigned short P[64][136];
    int lane = threadIdx.x & 63;
    int wave = threadIdx.x >> 6;
    int m = lane & 15, q = lane >> 4;
    int rowBase = blockIdx.x * 64 + wave * 16;
    int arow = rowBase + m;
    int arowc = (arow < NN) ? arow : (NN - 1);

    floatx4 acc[8];
#pragma unroll
    for (int t = 0; t < 8; t++) acc[t] = (floatx4){0.f, 0.f, 0.f, 0.f};

#pragma unroll
    for (int k0 = 0; k0 < 128; k0 += 32) {
        bf16x8 a = load16(hb + (size_t)arowc * 128 + k0 + q * 8);
#pragma unroll
        for (int t = 0; t < 8; t++) {
            int n = t * 16 + m;
            bf16x8 b = loaddw(l1wb + (size_t)n * 130 + 2 + k0 + q * 8);
            acc[t] = __builtin_amdgcn_mfma_f32_16x16x32_bf16(a, b, acc[t], 0, 0, 0);
        }
    }

    int r0 = rowBase + q * 4;
    float s0[4], s1[4];
#pragma unroll
    for (int j = 0; j < 4; j++) {
        int r = r0 + j; int rc = (r < NN) ? r : (NN - 1);
        int g = clampi(batch[rc], BB - 1);
        s0[j] = stateBuf[g * 2 + 0];
        s1[j] = stateBuf[g * 2 + 1];
    }
#pragma unroll
    for (int t = 0; t < 8; t++) {
        int c = t * 16 + m;
        float w0 = lin1w[(size_t)c * 130 + 0];
        float w1 = lin1w[(size_t)c * 130 + 1];
        float bb = lin1b[c];
#pragma unroll
        for (int j = 0; j < 4; j++) {
            int r = r0 + j;
            float v = acc[t][j] + bb + s0[j] * w0 + s1[j] * w1;
            if (r < NN) h2f[(size_t)r * 128 + c] = v;
            P[wave * 16 + q * 4 + j][c] = f2bf(v);
        }
    }
    __syncthreads();

    floatx4 acc2[8];
#pragma unroll
    for (int t = 0; t < 8; t++) acc2[t] = (floatx4){0.f, 0.f, 0.f, 0.f};
#pragma unroll
    for (int k0 = 0; k0 < 128; k0 += 32) {
        FragU fa; fa.q = *(const uint4*)&P[wave * 16 + m][k0 + q * 8];
#pragma unroll
        for (int t = 0; t < 8; t++) {
            int n = t * 16 + m;
            bf16x8 b = load16(c1wb + (size_t)n * 128 + k0 + q * 8);
            acc2[t] = __builtin_amdgcn_mfma_f32_16x16x32_bf16(fa.v, b, acc2[t], 0, 0, 0);
        }
    }
#pragma unroll
    for (int t = 0; t < 8; t++) {
        int c = t * 16 + m;
#pragma unroll
        for (int j = 0; j < 4; j++) {
            int r = r0 + j;
            if (r < NN) xfb[(size_t)r * 128 + c] = f2bf(acc2[t][j]);
        }
    }
}

// ---------------- kE2: sorted-edge MLP + gather-multiply + LDS-slot scatter ----------------
__global__ __launch_bounds__(256) void kE2(const float* __restrict__ ea,            // [E,50] fp32
                                           const unsigned short* __restrict__ w1b,  // [128,50] bf16
                                           const float* __restrict__ b1,
                                           const unsigned short* __restrict__ w2b,  // [128,128] bf16
                                           const float* __restrict__ b2,
                                           const int* __restrict__ ePerm,
                                           const int* __restrict__ dstS,
                                           const int* __restrict__ srcS,
                                           const float* __restrict__ cS,
                                           const unsigned short* __restrict__ xfb,  // [N,128] bf16
                                           float* __restrict__ agg) {               // [N,128] fp32
    __shared__ __align__(16) unsigned short P[64][136];
    __shared__ float accS[64][132];
    __shared__ int sSlot[64];
    __shared__ int sSlotDst[64];
    __shared__ int sD;

    int tid = threadIdx.x;
    int lane = tid & 63;
    int wave = tid >> 6;
    int m = lane & 15, q = lane >> 4;
    int base = blockIdx.x * 64;

    // zero LDS accumulator
    float* accFlat = &accS[0][0];
    for (int i = tid; i < 64 * 132; i += 256) accFlat[i] = 0.f;

    // wave 0: per-block slot ids via ballot over the 64 sorted dsts
    if (tid < 64) {
        int i = tid;
        int di = dstS[base + i];
        bool flag = (i == 0) || (di != dstS[base + i - 1]);
        unsigned long long bm = __ballot(flag ? 1 : 0);
        unsigned long long low = (i == 63) ? ~0ull : ((1ull << (i + 1)) - 1ull);
        int slot = (int)__popcll(bm & low) - 1;
        sSlot[i] = slot;
        if (flag) sSlotDst[slot] = di;
        if (i == 63) sD = slot + 1;
    }

    int eRow = ePerm[base + wave * 16 + m];

    floatx4 acc[8];
#pragma unroll
    for (int t = 0; t < 8; t++) acc[t] = (floatx4){0.f, 0.f, 0.f, 0.f};

    // GEMM1: ea[e] @ w1^T, K padded 50->64
    {   // k0 = 0: k in [0,32) all valid
        bf16x8 a = f8frag(ea + (size_t)eRow * 50 + q * 8);
#pragma unroll
        for (int t = 0; t < 8; t++) {
            int n = t * 16 + m;
            bf16x8 b = loaddw(w1b + (size_t)n * 50 + q * 8);
            acc[t] = __builtin_amdgcn_mfma_f32_16x16x32_bf16(a, b, acc[t], 0, 0, 0);
        }
    }
    {   // k0 = 32: mask k >= 50
        int kbase = 32 + q * 8;
        FragU fa;
        const float* pa = ea + (size_t)eRow * 50 + kbase;
#pragma unroll
        for (int j = 0; j < 8; j++) fa.u[j] = (kbase + j < 50) ? f2bf(pa[j]) : 0;
#pragma unroll
        for (int t = 0; t < 8; t++) {
            int n = t * 16 + m;
            FragU fb;
            const unsigned int* pb = (const unsigned int*)(w1b + (size_t)n * 50 + kbase);
#pragma unroll
            for (int t2 = 0; t2 < 4; t2++) fb.d[t2] = (kbase + 2 * t2 < 50) ? pb[t2] : 0u;
            acc[t] = __builtin_amdgcn_mfma_f32_16x16x32_bf16(fa.v, fb.v, acc[t], 0, 0, 0);
        }
    }

    // P = ssp(acc + b1) -> LDS
#pragma unroll
    for (int t = 0; t < 8; t++) {
        int c = t * 16 + m;
        float bb = b1[c];
#pragma unroll
        for (int j = 0; j < 4; j++)
            P[wave * 16 + q * 4 + j][c] = f2bf(sspf(acc[t][j] + bb));
    }
    __syncthreads();

    // GEMM2: P @ w2^T
    floatx4 acc2[8];
#pragma unroll
    for (int t = 0; t < 8; t++) acc2[t] = (floatx4){0.f, 0.f, 0.f, 0.f};
#pragma unroll
    for (int k0 = 0; k0 < 128; k0 += 32) {
        FragU fa; fa.q = *(const uint4*)&P[wave * 16 + m][k0 + q * 8];
#pragma unroll
        for (int t = 0; t < 8; t++) {
            int n = t * 16 + m;
            bf16x8 b = load16(w2b + (size_t)n * 128 + k0 + q * 8);
            acc2[t] = __builtin_amdgcn_mfma_f32_16x16x32_bf16(fa.v, b, acc2[t], 0, 0, 0);
        }
    }

    // epilogue: msg -> LDS slot accumulator (run-combined in-register)
    int sl[4], srcj[4]; float Cj[4];
#pragma unroll
    for (int j = 0; j < 4; j++) {
        int r = wave * 16 + q * 4 + j;
        int g = base + r;
        sl[j] = sSlot[r];
        Cj[j] = cS[g];
        srcj[j] = srcS[g];
    }
#pragma unroll
    for (int t = 0; t < 8; t++) {
        int c = t * 16 + m;
        float bb = b2[c];
        float v4[4];
#pragma unroll
        for (int j = 0; j < 4; j++)
            v4[j] = (acc2[t][j] + bb) * Cj[j] * bf2f(xfb[(size_t)srcj[j] * 128 + c]);
        float run = v4[0];
#pragma unroll
        for (int j = 1; j < 4; j++) {
            if (sl[j] == sl[j - 1]) run += v4[j];
            else { atomicAdd(&accS[sl[j - 1]][c], run); run = v4[j]; }
        }
        atomicAdd(&accS[sl[3]][c], run);
    }
    __syncthreads();

    // flush distinct rows to global
    int D = sD;
    for (int idx = tid; idx < D * 128; idx += 256) {
        int s = idx >> 7, c = idx & 127;
        unsafeAtomicAdd(&agg[(size_t)sSlotDst[s] * 128 + c], accS[s][c]);
    }
}

// ---------------- kC: xc = conv_lin2(agg); h = h2 + ssp(xc); pooling ----------------
__global__ __launch_bounds__(256) void kC(const float* __restrict__ agg,           // [N,128] fp32
                                          const unsigned short* __restrict__ wb,   // [128,128] bf16
                                          const float* __restrict__ b,
                                          const float* __restrict__ h2f,
                                          unsigned short* __restrict__ hnb,        // [N,128] bf16 out
                                          const int* __restrict__ batch,
                                          float* __restrict__ pool,
                                          int doPool) {
    int lane = threadIdx.x & 63;
    int wave = threadIdx.x >> 6;
    int m = lane & 15, q = lane >> 4;
    int rowBase = blockIdx.x * 64 + wave * 16;
    int arow = rowBase + m;
    int arowc = (arow < NN) ? arow : (NN - 1);

    floatx4 acc[8];
#pragma unroll
    for (int t = 0; t < 8; t++) acc[t] = (floatx4){0.f, 0.f, 0.f, 0.f};

#pragma unroll
    for (int k0 = 0; k0 < 128; k0 += 32) {
        bf16x8 fa = f8frag(agg + (size_t)arowc * 128 + k0 + q * 8);
#pragma unroll
        for (int t = 0; t < 8; t++) {
            int n = t * 16 + m;
            bf16x8 bfr = load16(wb + (size_t)n * 128 + k0 + q * 8);
            acc[t] = __builtin_amdgcn_mfma_f32_16x16x32_bf16(fa, bfr, acc[t], 0, 0, 0);
        }
    }

    int r0 = rowBase + q * 4;
    float vsum[4] = {0.f, 0.f, 0.f, 0.f};
#pragma unroll
    for (int t = 0; t < 8; t++) {
        int c = t * 16 + m;
        float bb = b[c];
#pragma unroll
        for (int j = 0; j < 4; j++) {
            int r = r0 + j; int rc = (r < NN) ? r : (NN - 1);
            float v = h2f[(size_t)rc * 128 + c] + sspf(acc[t][j] + bb);
            if (r < NN) {
                hnb[(size_t)r * 128 + c] = f2bf(v);
                vsum[j] += v;
            }
        }
    }
    if (doPool) {
#pragma unroll
        for (int j = 0; j < 4; j++) {
            float v = vsum[j];
#pragma unroll
            for (int off = 1; off < 16; off <<= 1) v += __shfl_xor(v, off, 16);
            int r = r0 + j;
            if (m == 0 && r < NN) unsafeAtomicAdd(&pool[clampi(batch[r], BB - 1)], v);
        }
    }
}

// ---------------- kS: state scalar = pooled mean row-sum ----------------
__global__ __launch_bounds__(256) void kS(const float* __restrict__ pool,
                                          const int* __restrict__ counts,
                                          float* __restrict__ stateBuf) {
    int b = threadIdx.x;
    if (b < BB) {
        float c = (float)counts[b];
        c = (c < 1.f) ? 1.f : c;
        float v = pool[b] / c;
        stateBuf[b * 2 + 0] = v;
        stateBuf[b * 2 + 1] = v;
    }
}

// ---------------- kOut: out = h @ out_w^T + out_b ----------------
__global__ __launch_bounds__(256) void kOut(const unsigned short* __restrict__ hnb,
                                            const unsigned short* __restrict__ owb, // [128,128] bf16
                                            const float* __restrict__ ob,
                                            float* __restrict__ out) {
    int lane = threadIdx.x & 63;
    int wave = threadIdx.x >> 6;
    int m = lane & 15, q = lane >> 4;
    int rowBase = blockIdx.x * 64 + wave * 16;
    int arow = rowBase + m;
    int arowc = (arow < NN) ? arow : (NN - 1);

    floatx4 acc[8];
#pragma unroll
    for (int t = 0; t < 8; t++) acc[t] = (floatx4){0.f, 0.f, 0.f, 0.f};
#pragma unroll
    for (int k0 = 0; k0 < 128; k0 += 32) {
        bf16x8 a = load16(hnb + (size_t)arowc * 128 + k0 + q * 8);
#pragma unroll
        for (int t = 0; t < 8; t++) {
            int n = t * 16 + m;
            bf16x8 bfr = load16(owb + (size_t)n * 128 + k0 + q * 8);
            acc[t] = __builtin_amdgcn_mfma_f32_16x16x32_bf16(a, bfr, acc[t], 0, 0, 0);
        }
    }
    int r0 = rowBase + q * 4;
#pragma unroll
    for (int t = 0; t < 8; t++) {
        int c = t * 16 + m;
        float bb = ob[c];
#pragma unroll
        for (int j = 0; j < 4; j++) {
            int r = r0 + j;
            if (r < NN) out[(size_t)r * 128 + c] = acc[t][j] + bb;
        }
    }
}

extern "C" void kernel_launch(void* const* d_in, const int* in_sizes, int n_in,
                              void* d_out, int out_size, void* d_ws, size_t ws_size,
                              hipStream_t stream) {
    const float* h     = (const float*)d_in[0];
    const float* ew    = (const float*)d_in[1];
    const float* ea    = (const float*)d_in[2];
    const float* sa    = (const float*)d_in[3];
    const float* lin1w = (const float*)d_in[4];   // [2,128,130]
    const float* lin1b = (const float*)d_in[5];
    const float* mw1   = (const float*)d_in[6];   // [2,128,50]
    const float* mb1   = (const float*)d_in[7];
    const float* mw2   = (const float*)d_in[8];   // [2,128,128]
    const float* mb2   = (const float*)d_in[9];
    const float* c1w   = (const float*)d_in[10];  // [2,128,128]
    const float* c2w   = (const float*)d_in[11];  // [2,128,128]
    const float* c2b   = (const float*)d_in[12];
    const float* outw  = (const float*)d_in[13];  // [128,128]
    const float* outb  = (const float*)d_in[14];
    const int* eidx    = (const int*)d_in[15];    // [2,E]
    const int* batch   = (const int*)d_in[16];    // [N]
    float* out = (float*)d_out;

    char* ws = (char*)d_ws;
    float*          h2f   = (float*)(ws);                       // 25.6 MB
    unsigned short* xfb   = (unsigned short*)(ws + 25600000);   // 12.8 MB
    float*          agg   = (float*)(ws + 38400000);            // 25.6 MB
    unsigned short* hnb   = (unsigned short*)(ws + 64000000);   // 12.8 MB
    int*            ePerm = (int*)(ws + 76800000);              // 3.2 MB
    int*            srcS  = (int*)(ws + 80000000);              // 3.2 MB
    int*            dstS  = (int*)(ws + 83200000);              // 3.2 MB
    float*          cS    = (float*)(ws + 86400000);            // 3.2 MB
    int*            cnt   = (int*)(ws + 89600000);              // 200 KB
    int*            off   = (int*)(ws + 89800000);              // 200 KB
    int*            cur   = (int*)(ws + 90000000);              // 200 KB
    unsigned short* wb    = (unsigned short*)(ws + 90200000);   // 322 KB bf16 weights
    float*          pool  = (float*)(ws + 90600000);
    int*            counts= (int*)(ws + 90601024);
    float*          stateBuf = (float*)(ws + 90602048);

    // bf16 weight banks (element offsets within wb)
    unsigned short* mw1b  = wb;                 // 2*128*50  = 12800
    unsigned short* mw2b  = wb + 12800;         // 2*128*128 = 32768
    unsigned short* c1wb  = wb + 45568;         // 32768
    unsigned short* c2wb  = wb + 78336;         // 32768
    unsigned short* l1wb  = wb + 111104;        // 2*128*130 = 33280
    unsigned short* owb   = wb + 144384;        // 16384

    hipMemsetAsync(cnt, 0, NN * 4, stream);
    hipMemsetAsync(cur, 0, NN * 4, stream);
    hipMemsetAsync(counts, 0, BB * 4, stream);
    hipMemsetAsync(pool, 0, BB * 4, stream);

    kPrep<<<(NN + 255) / 256, 256, 0, stream>>>(batch, counts, sa, stateBuf);
    kHist<<<1024, 256, 0, stream>>>(eidx, cnt);
    kScan<<<1, 1024, 0, stream>>>(cnt, off);
    kScatter<<<1024, 256, 0, stream>>>(eidx, ew, off, cur, ePerm, dstS, srcS, cS);

    kConv<<<64, 256, 0, stream>>>(mw1, mw1b, 12800);
    kConv<<<128, 256, 0, stream>>>(mw2, mw2b, 32768);
    kConv<<<128, 256, 0, stream>>>(c1w, c1wb, 32768);
    kConv<<<128, 256, 0, stream>>>(c2w, c2wb, 32768);
    kConv<<<128, 256, 0, stream>>>(lin1w, l1wb, 33280);
    kConv<<<64, 256, 0, stream>>>(outw, owb, 16384);
    kConv<<<4096, 256, 0, stream>>>(h, hnb, NN * 128);   // h -> bf16 (layer-1 input)

    const int gridN = (NN + 63) / 64;   // 782
    const int gridE = EE / 64;          // 12500

    for (int i = 0; i < 2; i++) {
        hipMemsetAsync(agg, 0, (size_t)NN * 128 * 4, stream);
        kA<<<gridN, 256, 0, stream>>>(hnb,
                                      l1wb + (size_t)i * 128 * 130,
                                      lin1w + (size_t)i * 128 * 130,
                                      lin1b + (size_t)i * 128,
                                      c1wb + (size_t)i * 128 * 128,
                                      stateBuf, batch, h2f, xfb);
        kE2<<<gridE, 256, 0, stream>>>(ea,
                                       mw1b + (size_t)i * 128 * 50,
                                       mb1 + (size_t)i * 128,
                                       mw2b + (size_t)i * 128 * 128,
                                       mb2 + (size_t)i * 128,
                                       ePerm, dstS, srcS, cS, xfb, agg);
        kC<<<gridN, 256, 0, stream>>>(agg,
                                      c2wb + (size_t)i * 128 * 128,
                                      c2b + (size_t)i * 128,
                                      h2f, hnb, batch, pool, (i == 0) ? 1 : 0);
        if (i == 0) kS<<<1, 256, 0, stream>>>(pool, counts, stateBuf);
    }
    kOut<<<gridN, 256, 0, stream>>>(hnb, owb, outb, out);
}

// Round 4
// 1631.752 us; speedup vs baseline: 1.3805x; 1.0464x over previous
//
#include <hip/hip_runtime.h>

#define NN 50000
#define EE 800000
#define HH 128
#define GG 50
#define FF 128
#define SS 2
#define BB 256

typedef short bf16x8 __attribute__((ext_vector_type(8)));
typedef float floatx4 __attribute__((ext_vector_type(4)));

union FragU { bf16x8 v; unsigned short u[8]; unsigned int d[4]; uint4 q; };

__device__ __forceinline__ float bf2f(unsigned short u) {
    union { unsigned int i; float f; } c; c.i = ((unsigned int)u) << 16; return c.f;
}
__device__ __forceinline__ unsigned short f2bf(float f) {
    union { float f; unsigned int i; } c; c.f = f;
    unsigned int i = c.i;
    unsigned int r = (i + 0x7fffu + ((i >> 16) & 1u)) >> 16;
    return (unsigned short)r;
}
__device__ __forceinline__ float sspf(float x) {
    float l = __logf(1.f + __expf(x));
    l = (x > 20.f) ? x : l;
    return l - 0.69314718056f;
}
__device__ __forceinline__ bf16x8 f8frag(const float* p) {       // fp32 -> bf16 frag
    FragU f;
#pragma unroll
    for (int j = 0; j < 8; j++) f.u[j] = f2bf(p[j]);
    return f.v;
}
__device__ __forceinline__ bf16x8 load16(const unsigned short* p) { // 16B-aligned bf16
    FragU f; f.q = *(const uint4*)p; return f.v;
}
__device__ __forceinline__ bf16x8 loaddw(const unsigned short* p) { // 4B-aligned bf16
    FragU f; const unsigned int* pp = (const unsigned int*)p;
#pragma unroll
    for (int t = 0; t < 4; t++) f.d[t] = pp[t];
    return f.v;
}
__device__ __forceinline__ int clampi(int v, int hi) {
    v = (v < 0) ? 0 : v;
    return (v > hi) ? hi : v;
}

// ---------------- kConv: fp32 -> bf16 bulk convert ----------------
__global__ __launch_bounds__(256) void kConv(const float* __restrict__ s,
                                             unsigned short* __restrict__ d, int n) {
    for (int i = blockIdx.x * 256 + threadIdx.x; i < n; i += gridDim.x * 256)
        d[i] = f2bf(s[i]);
}

// ---------------- kConvW: all 6 weight arrays -> bf16 bank ----------------
__global__ __launch_bounds__(256) void kConvW(const float* __restrict__ a0,  // mw1 12800
                                              const float* __restrict__ a1,  // mw2 32768
                                              const float* __restrict__ a2,  // c1w 32768
                                              const float* __restrict__ a3,  // c2w 32768
                                              const float* __restrict__ a4,  // lin1w 33280
                                              const float* __restrict__ a5,  // outw 16384
                                              unsigned short* __restrict__ d) {
    int i = blockIdx.x * 256 + threadIdx.x;   // grid covers 160768 exactly
    float v;
    if (i < 12800)        v = a0[i];
    else if (i < 45568)   v = a1[i - 12800];
    else if (i < 78336)   v = a2[i - 45568];
    else if (i < 111104)  v = a3[i - 78336];
    else if (i < 144384)  v = a4[i - 111104];
    else                  v = a5[i - 144384];
    d[i] = f2bf(v);
}

// ---------------- kPrep: batch histogram + state init ----------------
__global__ __launch_bounds__(256) void kPrep(const int* __restrict__ batch,
                                             int* __restrict__ counts,
                                             const float* __restrict__ sa_in,
                                             float* __restrict__ stateBuf) {
    int i = blockIdx.x * 256 + threadIdx.x;
    if (i < NN) atomicAdd(&counts[clampi(batch[i], BB - 1)], 1);
    if (i < BB * SS) stateBuf[i] = sa_in[i];
}

// ---------------- kHist: edges-per-dst histogram ----------------
__global__ __launch_bounds__(256) void kHist(const int* __restrict__ eidx,
                                             int* __restrict__ cnt) {
    for (int e = blockIdx.x * 256 + threadIdx.x; e < EE; e += gridDim.x * 256)
        atomicAdd(&cnt[clampi(eidx[EE + e], NN - 1)], 1);
}

// ---------------- 3-phase multi-block exclusive scan ----------------
__global__ __launch_bounds__(1024) void kScanA(const int* __restrict__ cnt,
                                               int* __restrict__ off,
                                               int* __restrict__ blkSum) {
    __shared__ int s[1024];
    int tid = threadIdx.x;
    int g = blockIdx.x * 1024 + tid;
    int v = (g < NN) ? cnt[g] : 0;
    s[tid] = v;
    __syncthreads();
#pragma unroll
    for (int o = 1; o < 1024; o <<= 1) {
        int x = (tid >= o) ? s[tid - o] : 0;
        __syncthreads();
        s[tid] += x;
        __syncthreads();
    }
    if (g < NN) off[g] = s[tid] - v;
    if (tid == 1023) blkSum[blockIdx.x] = s[1023];
}
__global__ void kScanB(int* __restrict__ blkSum, int nb) {
    if (threadIdx.x == 0) {
        int acc = 0;
        for (int i = 0; i < nb; i++) { int t = blkSum[i]; blkSum[i] = acc; acc += t; }
    }
}
__global__ __launch_bounds__(256) void kScanC(int* __restrict__ off,
                                              const int* __restrict__ blkSum) {
    int g = blockIdx.x * 256 + threadIdx.x;
    if (g < NN) off[g] += blkSum[g >> 10];
}

// ---------------- kScatter: pos[e] + sorted dst/src/C arrays ----------------
__global__ __launch_bounds__(256) void kScatter(const int* __restrict__ eidx,
                                                const float* __restrict__ ew,
                                                const int* __restrict__ off,
                                                int* __restrict__ cur,
                                                int* __restrict__ pos,
                                                int* __restrict__ ePerm,
                                                int* __restrict__ dstS,
                                                int* __restrict__ srcS,
                                                float* __restrict__ cS) {
    for (int e = blockIdx.x * 256 + threadIdx.x; e < EE; e += gridDim.x * 256) {
        int d = clampi(eidx[EE + e], NN - 1);
        int p = off[d] + atomicAdd(&cur[d], 1);
        pos[e] = p;
        ePerm[p] = e;
        dstS[p] = d;
        srcS[p] = clampi(eidx[e], NN - 1);
        float w = ew[e];
        cS[p] = 0.5f * (__cosf(w * 0.62831853072f) + 1.f);
    }
}

// ---------------- kA: h2 = lin1([sa,h]) ; xf = conv_lin1(h2) ----------------
__global__ __launch_bounds__(256) void kA(const unsigned short* __restrict__ hb,   // [N,128] bf16
                                          const unsigned short* __restrict__ l1wb, // [128,130] bf16
                                          const float* __restrict__ lin1w,         // [128,130] fp32
                                          const float* __restrict__ lin1b,
                                          const unsigned short* __restrict__ c1wb, // [128,128] bf16
                                          const float* __restrict__ stateBuf,
                                          const int* __restrict__ batch,
                                          unsigned short* __restrict__ h2b,        // [N,128] bf16
                                          unsigned short* __restrict__ xfb) {      // [N,128] bf16
    __shared__ __align__(16) unsigned short P[64][136];
    int lane = threadIdx.x & 63;
    int wave = threadIdx.x >> 6;
    int m = lane & 15, q = lane >> 4;
    int rowBase = blockIdx.x * 64 + wave * 16;
    int arow = rowBase + m;
    int arowc = (arow < NN) ? arow : (NN - 1);

    floatx4 acc[8];
#pragma unroll
    for (int t = 0; t < 8; t++) acc[t] = (floatx4){0.f, 0.f, 0.f, 0.f};

#pragma unroll
    for (int k0 = 0; k0 < 128; k0 += 32) {
        bf16x8 a = load16(hb + (size_t)arowc * 128 + k0 + q * 8);
#pragma unroll
        for (int t = 0; t < 8; t++) {
            int n = t * 16 + m;
            bf16x8 b = loaddw(l1wb + (size_t)n * 130 + 2 + k0 + q * 8);
            acc[t] = __builtin_amdgcn_mfma_f32_16x16x32_bf16(a, b, acc[t], 0, 0, 0);
        }
    }

    int r0 = rowBase + q * 4;
    float s0[4], s1[4];
#pragma unroll
    for (int j = 0; j < 4; j++) {
        int r = r0 + j; int rc = (r < NN) ? r : (NN - 1);
        int g = clampi(batch[rc], BB - 1);
        s0[j] = stateBuf[g * 2 + 0];
        s1[j] = stateBuf[g * 2 + 1];
    }
#pragma unroll
    for (int t = 0; t < 8; t++) {
        int c = t * 16 + m;
        float w0 = lin1w[(size_t)c * 130 + 0];
        float w1 = lin1w[(size_t)c * 130 + 1];
        float bb = lin1b[c];
#pragma unroll
        for (int j = 0; j < 4; j++) {
            int r = r0 + j;
            unsigned short vb = f2bf(acc[t][j] + bb + s0[j] * w0 + s1[j] * w1);
            if (r < NN) h2b[(size_t)r * 128 + c] = vb;
            P[wave * 16 + q * 4 + j][c] = vb;
        }
    }
    __syncthreads();

    floatx4 acc2[8];
#pragma unroll
    for (int t = 0; t < 8; t++) acc2[t] = (floatx4){0.f, 0.f, 0.f, 0.f};
#pragma unroll
    for (int k0 = 0; k0 < 128; k0 += 32) {
        FragU fa; fa.q = *(const uint4*)&P[wave * 16 + m][k0 + q * 8];
#pragma unroll
        for (int t = 0; t < 8; t++) {
            int n = t * 16 + m;
            bf16x8 b = load16(c1wb + (size_t)n * 128 + k0 + q * 8);
            acc2[t] = __builtin_amdgcn_mfma_f32_16x16x32_bf16(fa.v, b, acc2[t], 0, 0, 0);
        }
    }
#pragma unroll
    for (int t = 0; t < 8; t++) {
        int c = t * 16 + m;
#pragma unroll
        for (int j = 0; j < 4; j++) {
            int r = r0 + j;
            if (r < NN) xfb[(size_t)r * 128 + c] = f2bf(acc2[t][j]);
        }
    }
}

// ---------------- kE_mlp: natural-order edge MLP -> W rows scattered to sorted pos ----------------
__global__ __launch_bounds__(256) void kE_mlp(const float* __restrict__ ea,           // [E,50] fp32
                                              const unsigned short* __restrict__ w1b, // [128,50]
                                              const float* __restrict__ b1,
                                              const unsigned short* __restrict__ w2b, // [128,128]
                                              const float* __restrict__ b2,
                                              const int* __restrict__ pos,            // [E]
                                              unsigned short* __restrict__ Wg,        // chunk buffer
                                              int pLo, int pHi) {
    __shared__ __align__(16) unsigned short P[64][136];
    int tid = threadIdx.x;
    int lane = tid & 63;
    int wave = tid >> 6;
    int m = lane & 15, q = lane >> 4;
    int base = blockIdx.x * 64;
    int eRow = base + wave * 16 + m;      // natural order: streaming ea reads

    floatx4 acc[8];
#pragma unroll
    for (int t = 0; t < 8; t++) acc[t] = (floatx4){0.f, 0.f, 0.f, 0.f};

    // GEMM1: ea @ w1^T, K padded 50->64
    {
        bf16x8 a = f8frag(ea + (size_t)eRow * 50 + q * 8);
#pragma unroll
        for (int t = 0; t < 8; t++) {
            int n = t * 16 + m;
            bf16x8 b = loaddw(w1b + (size_t)n * 50 + q * 8);
            acc[t] = __builtin_amdgcn_mfma_f32_16x16x32_bf16(a, b, acc[t], 0, 0, 0);
        }
    }
    {
        int kbase = 32 + q * 8;
        FragU fa;
        const float* pa = ea + (size_t)eRow * 50 + kbase;
#pragma unroll
        for (int j = 0; j < 8; j++) fa.u[j] = (kbase + j < 50) ? f2bf(pa[j]) : 0;
#pragma unroll
        for (int t = 0; t < 8; t++) {
            int n = t * 16 + m;
            FragU fb;
            const unsigned int* pb = (const unsigned int*)(w1b + (size_t)n * 50 + kbase);
#pragma unroll
            for (int t2 = 0; t2 < 4; t2++) fb.d[t2] = (kbase + 2 * t2 < 50) ? pb[t2] : 0u;
            acc[t] = __builtin_amdgcn_mfma_f32_16x16x32_bf16(fa.v, fb.v, acc[t], 0, 0, 0);
        }
    }

    // P = ssp(acc + b1)
#pragma unroll
    for (int t = 0; t < 8; t++) {
        int c = t * 16 + m;
        float bb = b1[c];
#pragma unroll
        for (int j = 0; j < 4; j++)
            P[wave * 16 + q * 4 + j][c] = f2bf(sspf(acc[t][j] + bb));
    }
    __syncthreads();

    // GEMM2: P @ w2^T
    floatx4 acc2[8];
#pragma unroll
    for (int t = 0; t < 8; t++) acc2[t] = (floatx4){0.f, 0.f, 0.f, 0.f};
#pragma unroll
    for (int k0 = 0; k0 < 128; k0 += 32) {
        FragU fa; fa.q = *(const uint4*)&P[wave * 16 + m][k0 + q * 8];
#pragma unroll
        for (int t = 0; t < 8; t++) {
            int n = t * 16 + m;
            bf16x8 b = load16(w2b + (size_t)n * 128 + k0 + q * 8);
            acc2[t] = __builtin_amdgcn_mfma_f32_16x16x32_bf16(fa.v, b, acc2[t], 0, 0, 0);
        }
    }
    __syncthreads();   // all P reads done

    // W = acc2 + b2 -> LDS (transpose to row-contiguous)
#pragma unroll
    for (int t = 0; t < 8; t++) {
        int c = t * 16 + m;
        float bb = b2[c];
#pragma unroll
        for (int j = 0; j < 4; j++)
            P[wave * 16 + q * 4 + j][c] = f2bf(acc2[t][j] + bb);
    }
    __syncthreads();

    // scatter-store rows to sorted positions, 64B per thread
    int r = tid >> 2, chunk = tid & 3;
    int p = pos[base + r];
    if (p >= pLo && p < pHi) {
        const uint4* s = (const uint4*)&P[r][chunk * 32];
        uint4* d = (uint4*)&Wg[((size_t)(p - pLo)) * 128 + chunk * 32];
        d[0] = s[0]; d[1] = s[1]; d[2] = s[2]; d[3] = s[3];
    }
}

// ---------------- kAgg: stream Wsorted, gather xf, reduce runs -> agg ----------------
__global__ __launch_bounds__(256) void kAgg(const unsigned short* __restrict__ Wg,
                                            const int* __restrict__ dstS,
                                            const int* __restrict__ srcS,
                                            const float* __restrict__ cS,
                                            const unsigned short* __restrict__ xfb,
                                            float* __restrict__ agg,
                                            int blockBase) {
    __shared__ float accS[64][128];
    __shared__ int sSlot[64];
    __shared__ int sSlotDst[64];
    __shared__ int sSrc[64];
    __shared__ float sC[64];
    __shared__ int sD;

    int tid = threadIdx.x;
    int gbase = (blockBase + blockIdx.x) * 64;   // sorted-global
    int lbase = blockIdx.x * 64;                 // chunk-local W rows

    if (tid < 64) {
        int i = tid;
        int di = dstS[gbase + i];
        sSrc[i] = srcS[gbase + i];
        sC[i] = cS[gbase + i];
        bool flag = (i == 0) || (di != dstS[gbase + i - 1]);
        unsigned long long bm = __ballot(flag ? 1 : 0);
        unsigned long long low = (i == 63) ? ~0ull : ((1ull << (i + 1)) - 1ull);
        int slot = (int)__popcll(bm & low) - 1;
        sSlot[i] = slot;
        if (flag) sSlotDst[slot] = di;
        if (i == 63) sD = slot + 1;
    }
    __syncthreads();
    int D = sD;
    float* accFlat = &accS[0][0];
    for (int i = tid; i < D * 128; i += 256) accFlat[i] = 0.f;
    __syncthreads();

    // each thread owns 2 columns over 16 rows; run-combine by slot
    int c2 = (tid & 63) * 2;
    int half = tid >> 6;
    int r0 = half * 16;
    float run0 = 0.f, run1 = 0.f;
    int prev = sSlot[r0];
#pragma unroll 4
    for (int r = r0; r < r0 + 16; r++) {
        int sl = sSlot[r];
        if (sl != prev) {
            atomicAdd(&accS[prev][c2], run0);
            atomicAdd(&accS[prev][c2 + 1], run1);
            run0 = run1 = 0.f;
            prev = sl;
        }
        unsigned int wv = *(const unsigned int*)&Wg[((size_t)(lbase + r)) * 128 + c2];
        unsigned int xv = *(const unsigned int*)&xfb[((size_t)sSrc[r]) * 128 + c2];
        float cc = sC[r];
        run0 += bf2f((unsigned short)wv) * cc * bf2f((unsigned short)xv);
        run1 += bf2f((unsigned short)(wv >> 16)) * cc * bf2f((unsigned short)(xv >> 16));
    }
    atomicAdd(&accS[prev][c2], run0);
    atomicAdd(&accS[prev][c2 + 1], run1);
    __syncthreads();

    // flush: interior slots fully owned -> plain store; boundary -> atomic
    for (int idx = tid; idx < D * 128; idx += 256) {
        int s = idx >> 7, cc = idx & 127;
        float v = accS[s][cc];
        size_t o = (size_t)sSlotDst[s] * 128 + cc;
        if (s > 0 && s < D - 1) agg[o] = v;
        else unsafeAtomicAdd(&agg[o], v);
    }
}

// ---------------- kE2 (fallback, round-3 fused) ----------------
__global__ __launch_bounds__(256) void kE2(const float* __restrict__ ea,
                                           const unsigned short* __restrict__ w1b,
                                           const float* __restrict__ b1,
                                           const unsigned short* __restrict__ w2b,
                                           const float* __restrict__ b2,
                                           const int* __restrict__ ePerm,
                                           const int* __restrict__ dstS,
                                           const int* __restrict__ srcS,
                                           const float* __restrict__ cS,
                                           const unsigned short* __restrict__ xfb,
                                           float* __restrict__ agg) {
    __shared__ __align__(16) unsigned short P[64][136];
    __shared__ float accS[64][132];
    __shared__ int sSlot[64];
    __shared__ int sSlotDst[64];
    __shared__ int sD;

    int tid = threadIdx.x;
    int lane = tid & 63;
    int wave = tid >> 6;
    int m = lane & 15, q = lane >> 4;
    int base = blockIdx.x * 64;

    float* accFlat = &accS[0][0];
    for (int i = tid; i < 64 * 132; i += 256) accFlat[i] = 0.f;

    if (tid < 64) {
        int i = tid;
        int di = dstS[base + i];
        bool flag = (i == 0) || (di != dstS[base + i - 1]);
        unsigned long long bm = __ballot(flag ? 1 : 0);
        unsigned long long low = (i == 63) ? ~0ull : ((1ull << (i + 1)) - 1ull);
        int slot = (int)__popcll(bm & low) - 1;
        sSlot[i] = slot;
        if (flag) sSlotDst[slot] = di;
        if (i == 63) sD = slot + 1;
    }

    int eRow = ePerm[base + wave * 16 + m];

    floatx4 acc[8];
#pragma unroll
    for (int t = 0; t < 8; t++) acc[t] = (floatx4){0.f, 0.f, 0.f, 0.f};
    {
        bf16x8 a = f8frag(ea + (size_t)eRow * 50 + q * 8);
#pragma unroll
        for (int t = 0; t < 8; t++) {
            int n = t * 16 + m;
            bf16x8 b = loaddw(w1b + (size_t)n * 50 + q * 8);
            acc[t] = __builtin_amdgcn_mfma_f32_16x16x32_bf16(a, b, acc[t], 0, 0, 0);
        }
    }
    {
        int kbase = 32 + q * 8;
        FragU fa;
        const float* pa = ea + (size_t)eRow * 50 + kbase;
#pragma unroll
        for (int j = 0; j < 8; j++) fa.u[j] = (kbase + j < 50) ? f2bf(pa[j]) : 0;
#pragma unroll
        for (int t = 0; t < 8; t++) {
            int n = t * 16 + m;
            FragU fb;
            const unsigned int* pb = (const unsigned int*)(w1b + (size_t)n * 50 + kbase);
#pragma unroll
            for (int t2 = 0; t2 < 4; t2++) fb.d[t2] = (kbase + 2 * t2 < 50) ? pb[t2] : 0u;
            acc[t] = __builtin_amdgcn_mfma_f32_16x16x32_bf16(fa.v, fb.v, acc[t], 0, 0, 0);
        }
    }
#pragma unroll
    for (int t = 0; t < 8; t++) {
        int c = t * 16 + m;
        float bb = b1[c];
#pragma unroll
        for (int j = 0; j < 4; j++)
            P[wave * 16 + q * 4 + j][c] = f2bf(sspf(acc[t][j] + bb));
    }
    __syncthreads();

    floatx4 acc2[8];
#pragma unroll
    for (int t = 0; t < 8; t++) acc2[t] = (floatx4){0.f, 0.f, 0.f, 0.f};
#pragma unroll
    for (int k0 = 0; k0 < 128; k0 += 32) {
        FragU fa; fa.q = *(const uint4*)&P[wave * 16 + m][k0 + q * 8];
#pragma unroll
        for (int t = 0; t < 8; t++) {
            int n = t * 16 + m;
            bf16x8 b = load16(w2b + (size_t)n * 128 + k0 + q * 8);
            acc2[t] = __builtin_amdgcn_mfma_f32_16x16x32_bf16(fa.v, b, acc2[t], 0, 0, 0);
        }
    }

    int sl[4], srcj[4]; float Cj[4];
#pragma unroll
    for (int j = 0; j < 4; j++) {
        int r = wave * 16 + q * 4 + j;
        int g = base + r;
        sl[j] = sSlot[r];
        Cj[j] = cS[g];
        srcj[j] = srcS[g];
    }
#pragma unroll
    for (int t = 0; t < 8; t++) {
        int c = t * 16 + m;
        float bb = b2[c];
        float v4[4];
#pragma unroll
        for (int j = 0; j < 4; j++)
            v4[j] = (acc2[t][j] + bb) * Cj[j] * bf2f(xfb[(size_t)srcj[j] * 128 + c]);
        float run = v4[0];
#pragma unroll
        for (int j = 1; j < 4; j++) {
            if (sl[j] == sl[j - 1]) run += v4[j];
            else { atomicAdd(&accS[sl[j - 1]][c], run); run = v4[j]; }
        }
        atomicAdd(&accS[sl[3]][c], run);
    }
    __syncthreads();

    int D = sD;
    for (int idx = tid; idx < D * 128; idx += 256) {
        int s = idx >> 7, c = idx & 127;
        unsafeAtomicAdd(&agg[(size_t)sSlotDst[s] * 128 + c], accS[s][c]);
    }
}

// ---------------- kC: xc = conv_lin2(agg); h = h2 + ssp(xc); pooling ----------------
__global__ __launch_bounds__(256) void kC(const float* __restrict__ agg,
                                          const unsigned short* __restrict__ wb,
                                          const float* __restrict__ b,
                                          const unsigned short* __restrict__ h2b,
                                          unsigned short* __restrict__ hnb,
                                          const int* __restrict__ batch,
                                          float* __restrict__ pool,
                                          int doPool) {
    int lane = threadIdx.x & 63;
    int wave = threadIdx.x >> 6;
    int m = lane & 15, q = lane >> 4;
    int rowBase = blockIdx.x * 64 + wave * 16;
    int arow = rowBase + m;
    int arowc = (arow < NN) ? arow : (NN - 1);

    floatx4 acc[8];
#pragma unroll
    for (int t = 0; t < 8; t++) acc[t] = (floatx4){0.f, 0.f, 0.f, 0.f};

#pragma unroll
    for (int k0 = 0; k0 < 128; k0 += 32) {
        bf16x8 fa = f8frag(agg + (size_t)arowc * 128 + k0 + q * 8);
#pragma unroll
        for (int t = 0; t < 8; t++) {
            int n = t * 16 + m;
            bf16x8 bfr = load16(wb + (size_t)n * 128 + k0 + q * 8);
            acc[t] = __builtin_amdgcn_mfma_f32_16x16x32_bf16(fa, bfr, acc[t], 0, 0, 0);
        }
    }

    int r0 = rowBase + q * 4;
    float vsum[4] = {0.f, 0.f, 0.f, 0.f};
#pragma unroll
    for (int t = 0; t < 8; t++) {
        int c = t * 16 + m;
        float bb = b[c];
#pragma unroll
        for (int j = 0; j < 4; j++) {
            int r = r0 + j; int rc = (r < NN) ? r : (NN - 1);
            float v = bf2f(h2b[(size_t)rc * 128 + c]) + sspf(acc[t][j] + bb);
            if (r < NN) {
                hnb[(size_t)r * 128 + c] = f2bf(v);
                vsum[j] += v;
            }
        }
    }
    if (doPool) {
#pragma unroll
        for (int j = 0; j < 4; j++) {
            float v = vsum[j];
#pragma unroll
            for (int off = 1; off < 16; off <<= 1) v += __shfl_xor(v, off, 16);
            int r = r0 + j;
            if (m == 0 && r < NN) unsafeAtomicAdd(&pool[clampi(batch[r], BB - 1)], v);
        }
    }
}

// ---------------- kS ----------------
__global__ __launch_bounds__(256) void kS(const float* __restrict__ pool,
                                          const int* __restrict__ counts,
                                          float* __restrict__ stateBuf) {
    int b = threadIdx.x;
    if (b < BB) {
        float c = (float)counts[b];
        c = (c < 1.f) ? 1.f : c;
        float v = pool[b] / c;
        stateBuf[b * 2 + 0] = v;
        stateBuf[b * 2 + 1] = v;
    }
}

// ---------------- kOut ----------------
__global__ __launch_bounds__(256) void kOut(const unsigned short* __restrict__ hnb,
                                            const unsigned short* __restrict__ owb,
                                            const float* __restrict__ ob,
                                            float* __restrict__ out) {
    int lane = threadIdx.x & 63;
    int wave = threadIdx.x >> 6;
    int m = lane & 15, q = lane >> 4;
    int rowBase = blockIdx.x * 64 + wave * 16;
    int arow = rowBase + m;
    int arowc = (arow < NN) ? arow : (NN - 1);

    floatx4 acc[8];
#pragma unroll
    for (int t = 0; t < 8; t++) acc[t] = (floatx4){0.f, 0.f, 0.f, 0.f};
#pragma unroll
    for (int k0 = 0; k0 < 128; k0 += 32) {
        bf16x8 a = load16(hnb + (size_t)arowc * 128 + k0 + q * 8);
#pragma unroll
        for (int t = 0; t < 8; t++) {
            int n = t * 16 + m;
            bf16x8 bfr = load16(owb + (size_t)n * 128 + k0 + q * 8);
            acc[t] = __builtin_amdgcn_mfma_f32_16x16x32_bf16(a, bfr, acc[t], 0, 0, 0);
        }
    }
    int r0 = rowBase + q * 4;
#pragma unroll
    for (int t = 0; t < 8; t++) {
        int c = t * 16 + m;
        float bb = ob[c];
#pragma unroll
        for (int j = 0; j < 4; j++) {
            int r = r0 + j;
            if (r < NN) out[(size_t)r * 128 + c] = acc[t][j] + bb;
        }
    }
}

extern "C" void kernel_launch(void* const* d_in, const int* in_sizes, int n_in,
                              void* d_out, int out_size, void* d_ws, size_t ws_size,
                              hipStream_t stream) {
    const float* h     = (const float*)d_in[0];
    const float* ew    = (const float*)d_in[1];
    const float* ea    = (const float*)d_in[2];
    const float* sa    = (const float*)d_in[3];
    const float* lin1w = (const float*)d_in[4];
    const float* lin1b = (const float*)d_in[5];
    const float* mw1   = (const float*)d_in[6];
    const float* mb1   = (const float*)d_in[7];
    const float* mw2   = (const float*)d_in[8];
    const float* mb2   = (const float*)d_in[9];
    const float* c1w   = (const float*)d_in[10];
    const float* c2w   = (const float*)d_in[11];
    const float* c2b   = (const float*)d_in[12];
    const float* outw  = (const float*)d_in[13];
    const float* outb  = (const float*)d_in[14];
    const int* eidx    = (const int*)d_in[15];
    const int* batch   = (const int*)d_in[16];
    float* out = (float*)d_out;

    char* ws = (char*)d_ws;
    unsigned short* hnb   = (unsigned short*)(ws);              // 12.8 MB
    unsigned short* h2b   = (unsigned short*)(ws + 12800000);   // 12.8 MB
    unsigned short* xfb   = (unsigned short*)(ws + 25600000);   // 12.8 MB
    float*          agg   = (float*)(ws + 38400000);            // 25.6 MB
    int*            pos   = (int*)(ws + 64000000);              // 3.2 MB
    int*            ePerm = (int*)(ws + 67200000);              // 3.2 MB
    int*            dstS  = (int*)(ws + 70400000);              // 3.2 MB
    int*            srcS  = (int*)(ws + 73600000);              // 3.2 MB
    float*          cS    = (float*)(ws + 76800000);            // 3.2 MB
    int*            cnt   = (int*)(ws + 80000000);              // 200 KB
    int*            off   = (int*)(ws + 80200000);              // 200 KB
    int*            cur   = (int*)(ws + 80400000);              // 200 KB
    int*            blkSum= (int*)(ws + 80600000);              // 256 B
    unsigned short* wb    = (unsigned short*)(ws + 80600512);   // 321,536 B
    float*          pool  = (float*)(ws + 80922048);
    int*            counts= (int*)(ws + 80923072);
    float*          stateBuf = (float*)(ws + 80924096);
    const size_t WOFF = 80926720;
    unsigned short* Wg = (unsigned short*)(ws + WOFF);

    // chunk count for the Wsorted buffer
    size_t wAvail = (ws_size > WOFF) ? ws_size - WOFF : 0;
    int NC;
    if (wAvail >= (size_t)EE * 128 * 2)          NC = 1;
    else if (wAvail >= (size_t)EE * 64 * 2)      NC = 2;
    else if (wAvail >= (size_t)EE * 32 * 2)      NC = 4;
    else                                         NC = 0;   // fallback: fused kE2

    // bf16 weight banks
    unsigned short* mw1b = wb;
    unsigned short* mw2b = wb + 12800;
    unsigned short* c1wb = wb + 45568;
    unsigned short* c2wb = wb + 78336;
    unsigned short* l1wb = wb + 111104;
    unsigned short* owb  = wb + 144384;

    hipMemsetAsync(cnt, 0, NN * 4, stream);
    hipMemsetAsync(cur, 0, NN * 4, stream);
    hipMemsetAsync(counts, 0, BB * 4, stream);
    hipMemsetAsync(pool, 0, BB * 4, stream);

    kPrep<<<(NN + 255) / 256, 256, 0, stream>>>(batch, counts, sa, stateBuf);
    kHist<<<1024, 256, 0, stream>>>(eidx, cnt);
    kScanA<<<(NN + 1023) / 1024, 1024, 0, stream>>>(cnt, off, blkSum);
    kScanB<<<1, 64, 0, stream>>>(blkSum, (NN + 1023) / 1024);
    kScanC<<<(NN + 255) / 256, 256, 0, stream>>>(off, blkSum);
    kScatter<<<1024, 256, 0, stream>>>(eidx, ew, off, cur, pos, ePerm, dstS, srcS, cS);

    kConvW<<<160768 / 256, 256, 0, stream>>>(mw1, mw2, c1w, c2w, lin1w, outw, wb);
    kConv<<<4096, 256, 0, stream>>>(h, hnb, NN * 128);

    const int gridN = (NN + 63) / 64;   // 782
    const int gridE = EE / 64;          // 12500

    for (int i = 0; i < 2; i++) {
        hipMemsetAsync(agg, 0, (size_t)NN * 128 * 4, stream);
        kA<<<gridN, 256, 0, stream>>>(hnb,
                                      l1wb + (size_t)i * 128 * 130,
                                      lin1w + (size_t)i * 128 * 130,
                                      lin1b + (size_t)i * 128,
                                      c1wb + (size_t)i * 128 * 128,
                                      stateBuf, batch, h2b, xfb);
        if (NC > 0) {
            int chunkE = EE / NC;
            for (int ch = 0; ch < NC; ch++) {
                int pLo = ch * chunkE, pHi = pLo + chunkE;
                kE_mlp<<<gridE, 256, 0, stream>>>(ea,
                                                  mw1b + (size_t)i * 128 * 50,
                                                  mb1 + (size_t)i * 128,
                                                  mw2b + (size_t)i * 128 * 128,
                                                  mb2 + (size_t)i * 128,
                                                  pos, Wg, pLo, pHi);
                kAgg<<<chunkE / 64, 256, 0, stream>>>(Wg, dstS, srcS, cS, xfb, agg, pLo / 64);
            }
        } else {
            kE2<<<gridE, 256, 0, stream>>>(ea,
                                           mw1b + (size_t)i * 128 * 50,
                                           mb1 + (size_t)i * 128,
                                           mw2b + (size_t)i * 128 * 128,
                                           mb2 + (size_t)i * 128,
                                           ePerm, dstS, srcS, cS, xfb, agg);
        }
        kC<<<gridN, 256, 0, stream>>>(agg,
                                      c2wb + (size_t)i * 128 * 128,
                                      c2b + (size_t)i * 128,
                                      h2b, hnb, batch, pool, (i == 0) ? 1 : 0);
        if (i == 0) kS<<<1, 256, 0, stream>>>(pool, counts, stateBuf);
    }
    kOut<<<gridN, 256, 0, stream>>>(hnb, owb, outb, out);
}